// Round 8
// baseline (359.723 us; speedup 1.0000x reference)
//
#include <hip/hip_runtime.h>
#include <hip/hip_bf16.h>

typedef unsigned short u16;
typedef unsigned int u32;

#define N_NODES 50000
#define N_EDGES 800000
#define DHID 256
#define NCHUNK 49  // ceil(50000/1024)

typedef __attribute__((ext_vector_type(8))) _Float16 f16x8;
typedef __attribute__((ext_vector_type(4))) float f32x4;
typedef __attribute__((ext_vector_type(2))) float f32x2;

// ---------- helpers ----------
__device__ __forceinline__ u16 f2bf(float f) {
    u32 u = __float_as_uint(f);
    u32 r = (u + 0x7FFFu + ((u >> 16) & 1u)) >> 16;
    return (u16)r;
}
__device__ __forceinline__ float bf2f(u32 bits16) {
    return __uint_as_float(bits16 << 16);
}
__device__ __forceinline__ u16 f2h(float f) {
    _Float16 h = (_Float16)f;
    union { _Float16 h; u16 u; } c; c.h = h;
    return c.u;
}
__device__ __forceinline__ void gl_lds16(const void* g, void* l) {
    __builtin_amdgcn_global_load_lds(
        (const __attribute__((address_space(1))) u32*)g,
        (__attribute__((address_space(3))) u32*)l, 16, 0, 0);
}

// ---------- fused prep: x -> f16, zero deg + 8 tile zero-rows, W -> W^T f16 ----------
#define SPLIT_BLKS 12500
#define ZERO_BLKS 196
__global__ void prep_fused(const float* __restrict__ x, u16* __restrict__ xf,
                           const float* __restrict__ W1, const float* __restrict__ W2,
                           u16* __restrict__ W1t, u16* __restrict__ W2t,
                           int* __restrict__ deg, u32* __restrict__ hs32) {
    const int b = blockIdx.x, tid = threadIdx.x;
    if (b < SPLIT_BLKS) {
        int i = b * 256 + tid;  // n4 = 3.2M exact
        float4 v = ((const float4*)x)[i];
        u16 h0 = f2h(v.x), h1 = f2h(v.y), h2 = f2h(v.z), h3 = f2h(v.w);
        uint2 hv;
        hv.x = (u32)h0 | ((u32)h1 << 16);
        hv.y = (u32)h2 | ((u32)h3 << 16);
        ((uint2*)xf)[i] = hv;
    } else if (b < SPLIT_BLKS + ZERO_BLKS) {
        int j = (b - SPLIT_BLKS) * 256 + tid;
        if (j < N_NODES) deg[j] = 0;
        if (j < 128) {  // zero row Nn of each of the 8 tiles (64 B each)
            int t = j >> 4, w = j & 15;
            hs32[((size_t)t * (N_NODES + 1) + N_NODES) * 16 + w] = 0;
        }
    } else {
        int idx = b - (SPLIT_BLKS + ZERO_BLKS);  // 0..511
        int y = idx >> 8, n = idx & 255, k = tid;
        const float* W = y ? W2 : W1;
        u16* o = y ? W2t : W1t;
        o[n * 256 + k] = f2h(W[k * 256 + n]);
    }
}

__global__ void deg_kernel(const int* __restrict__ dst, int* __restrict__ deg, int E) {
    int e = blockIdx.x * 256 + threadIdx.x;
    if (e < E) atomicAdd(&deg[dst[e]], 1);
}

// chunked scan, step 1: inclusive scan within each 1024-chunk + chunk totals
__global__ __launch_bounds__(1024) void scan1_kernel(const int* __restrict__ deg,
                                                     int* __restrict__ partial,
                                                     int* __restrict__ totals, int n) {
    __shared__ int wsum[16];
    __shared__ int woff[16];
    const int tid = threadIdx.x, lane = tid & 63, wid = tid >> 6;
    const int idx = blockIdx.x * 1024 + tid;
    int v = (idx < n) ? deg[idx] : 0;
    int x = v;
#pragma unroll
    for (int off = 1; off < 64; off <<= 1) {
        int t = __shfl_up(x, off, 64);
        if (lane >= off) x += t;
    }
    if (lane == 63) wsum[wid] = x;
    __syncthreads();
    if (tid == 0) {
        int s = 0;
#pragma unroll
        for (int w = 0; w < 16; ++w) { woff[w] = s; s += wsum[w]; }
    }
    __syncthreads();
    x += woff[wid];
    partial[idx] = x;
    if (tid == 1023) totals[blockIdx.x] = x;
}

// step 2+3 fused: re-scan 49 totals in wave 0; rptr = chunkoff + inclusive - deg
__global__ void scan3_kernel(const int* __restrict__ deg, const int* __restrict__ partial,
                             const int* __restrict__ totals, int* __restrict__ rptr,
                             int* __restrict__ cursor, int n) {
    __shared__ int coff_s;
    const int tid = threadIdx.x;
    const int mychunk = blockIdx.x >> 2;
    if (tid < 64) {
        int v = (tid < NCHUNK) ? totals[tid] : 0;
        int x = v;
#pragma unroll
        for (int off = 1; off < 64; off <<= 1) {
            int t = __shfl_up(x, off, 64);
            if (tid >= off) x += t;
        }
        if (tid == mychunk) coff_s = x - v;
    }
    __syncthreads();
    int i = blockIdx.x * 256 + tid;
    if (i < n) {
        int e = coff_s + partial[i] - deg[i];
        rptr[i] = e;
        cursor[i] = e;
    }
    if (i == 0) rptr[n] = N_EDGES;
}

// CSR fill with u16 column ids (node ids < 65536)
__global__ void fill_kernel(const int* __restrict__ src, const int* __restrict__ dst,
                            int* __restrict__ cursor, u16* __restrict__ col16, int E) {
    int e = blockIdx.x * 256 + threadIdx.x;
    if (e < E) {
        int p = atomicAdd(&cursor[dst[e]], 1);
        col16[p] = (u16)src[e];
    }
}

// ---------- GEMM (f16): hs = (A @ W) * rsqrt(deg[row]+1), bf16 TILE-MAJOR out ----------
// out layout: [8 tiles of 32 cols][Nn+1][32] — row Nn per tile stays zero.
__global__ __launch_bounds__(256) void gemm_f16_kernel(
    const u16* __restrict__ Af, const u16* __restrict__ Bt,
    const int* __restrict__ deg, u16* __restrict__ out, int M) {
    __shared__ u16 As[128 * 32];
    __shared__ u16 Bs[128 * 32];
    const int tid = threadIdx.x;
    const int wave = tid >> 6;
    const int lane = tid & 63;
    const int wm = wave >> 1, wn = wave & 1;
    const int quad = lane >> 4, l16 = lane & 15;
    const int m0 = blockIdx.x * 128;
    const int n0 = blockIdx.y * 128;

    f32x4 acc[4][4] = {};

    const int row0 = tid >> 2, row1 = (256 + tid) >> 2;
    const int kk = (tid & 3) * 8;
    int ar0 = m0 + row0; if (ar0 >= M) ar0 = M - 1;
    int ar1 = m0 + row1; if (ar1 >= M) ar1 = M - 1;
    const size_t aoff0 = (size_t)ar0 * 256 + kk;
    const size_t aoff1 = (size_t)ar1 * 256 + kk;
    const size_t boff0 = (size_t)(n0 + row0) * 256 + kk;
    const size_t boff1 = (size_t)(n0 + row1) * 256 + kk;
    const size_t l0 = (size_t)(wave * 64) * 8;
    const size_t l1 = (size_t)(256 + wave * 64) * 8;

    for (int ko = 0; ko < 8; ++ko) {
        const int koff = ko * 32;
        __syncthreads();
        gl_lds16(Af + aoff0 + koff, &As[l0]);
        gl_lds16(Af + aoff1 + koff, &As[l1]);
        gl_lds16(Bt + boff0 + koff, &Bs[l0]);
        gl_lds16(Bt + boff1 + koff, &Bs[l1]);
        asm volatile("s_waitcnt vmcnt(0)" ::: "memory");
        __syncthreads();

        f16x8 af[4], bf[4];
#pragma unroll
        for (int mi = 0; mi < 4; ++mi)
            af[mi] = *(const f16x8*)&As[(wm * 64 + mi * 16 + l16) * 32 + quad * 8];
#pragma unroll
        for (int ni = 0; ni < 4; ++ni)
            bf[ni] = *(const f16x8*)&Bs[(wn * 64 + ni * 16 + l16) * 32 + quad * 8];
#pragma unroll
        for (int mi = 0; mi < 4; ++mi)
#pragma unroll
            for (int ni = 0; ni < 4; ++ni)
                acc[mi][ni] = __builtin_amdgcn_mfma_f32_16x16x32_f16(af[mi], bf[ni], acc[mi][ni], 0, 0, 0);
    }

#pragma unroll
    for (int mi = 0; mi < 4; ++mi) {
#pragma unroll
        for (int r = 0; r < 4; ++r) {
            int row = m0 + wm * 64 + mi * 16 + quad * 4 + r;
            if (row < M) {
                float s = rsqrtf((float)deg[row] + 1.0f);
#pragma unroll
                for (int ni = 0; ni < 4; ++ni) {
                    int c = n0 + wn * 64 + ni * 16 + l16;
                    out[((size_t)(c >> 5) * (N_NODES + 1) + row) * 32 + (c & 31)] =
                        f2bf(acc[mi][ni][r] * s);
                }
            }
        }
    }
}

// ---------- aggregation v6: column-tiled (XCD-pinned) + 8 nodes/wave lane-groups ----
// Wave = 8 nodes x 1 tile (tile = blockIdx & 7). Lane-group g (8 lanes) owns node
// base+g; per step one wave load = 8 nodes x 64 B slices. No cross-lane reduce.
// Loop to max deg over the 8 nodes; pad = zero row (row Nn of tile). Self added last.
__global__ __launch_bounds__(256) void agg_kernel(
    const u16* __restrict__ hs, const int* __restrict__ rptr, const u16* __restrict__ col16,
    const float* __restrict__ bias,
    u16* __restrict__ out_f16, float* __restrict__ out_f,
    int mode, int Nn) {
    const int wave = threadIdx.x >> 6, lane = threadIdx.x & 63;
    const int t = blockIdx.x & 7;
    const int g = lane >> 3, ql = lane & 7;
    const int i = (blockIdx.x >> 3) * 32 + wave * 8 + g;
    const bool valid = (i < Nn);
    const int ii = valid ? i : (Nn - 1);
    const int beg = rptr[ii];
    const int cnt = rptr[ii + 1] - beg;
    int mc = cnt;
    mc = max(mc, __shfl_xor(mc, 8, 64));
    mc = max(mc, __shfl_xor(mc, 16, 64));
    mc = max(mc, __shfl_xor(mc, 32, 64));
    const u16* tbase = hs + (size_t)t * (N_NODES + 1) * 32;
    const int lq = ql * 4;  // u16 offset within 32-col row

    f32x2 a01 = {0.f, 0.f}, a23 = {0.f, 0.f};
    const uint2 vself = *(const uint2*)(tbase + (size_t)ii * 32 + lq);

#define GIDX(j, e)                                                      \
    {                                                                   \
        int p = min((j), cnt - 1); p = max(p, 0);                       \
        int id = (int)col16[beg + p];                                   \
        e = ((j) < cnt) ? id : Nn;                                      \
    }
#define LOADP(e) (*(const uint2*)(tbase + (size_t)(e) * 32 + lq))
#define ACCUM(v)                                                        \
    {                                                                   \
        f32x2 p0, p1;                                                   \
        p0.x = __uint_as_float(v.x << 16);                              \
        p0.y = __uint_as_float(v.x & 0xffff0000u);                      \
        p1.x = __uint_as_float(v.y << 16);                              \
        p1.y = __uint_as_float(v.y & 0xffff0000u);                      \
        a01 += p0; a23 += p1;                                           \
    }

    if (mc > 0) {
        int e1;
        uint2 vA;
        { int e0; GIDX(0, e0); vA = LOADP(e0); }
        GIDX(1, e1);
        for (int j = 0; j < mc; ++j) {
            uint2 vB = {0, 0};
            int e2 = Nn;
            if (j + 1 < mc) {  // wave-uniform branch (mc is wave-max)
                vB = LOADP(e1);
                GIDX(j + 2, e2);
            }
            ACCUM(vA);
            vA = vB; e1 = e2;
        }
    }
    ACCUM(vself);
#undef GIDX
#undef LOADP
#undef ACCUM

    const float inv = rsqrtf((float)cnt + 1.0f);
    const float4 bb = *(const float4*)(bias + t * 32 + lq);
    float r0 = fmaxf(fmaf(a01.x, inv, bb.x), 0.0f);
    float r1 = fmaxf(fmaf(a01.y, inv, bb.y), 0.0f);
    float r2 = fmaxf(fmaf(a23.x, inv, bb.z), 0.0f);
    float r3 = fmaxf(fmaf(a23.y, inv, bb.w), 0.0f);

    if (valid) {
        const size_t o = (size_t)i * 256 + t * 32 + lq;  // node-major output
        if (mode == 0) {
            u16 h0 = f2h(r0), h1 = f2h(r1), h2 = f2h(r2), h3 = f2h(r3);
            uint2 w;
            w.x = (u32)h0 | ((u32)h1 << 16);
            w.y = (u32)h2 | ((u32)h3 << 16);
            *(uint2*)(out_f16 + o) = w;
        } else {
            *(float4*)(out_f + o) = make_float4(r0, r1, r2, r3);
        }
    }
}

extern "C" void kernel_launch(void* const* d_in, const int* in_sizes, int n_in,
                              void* d_out, int out_size, void* d_ws, size_t ws_size,
                              hipStream_t stream) {
    const float* x = (const float*)d_in[0];
    const int* ei = (const int*)d_in[1];
    const float* W1 = (const float*)d_in[2];
    const float* b1 = (const float*)d_in[3];
    const float* W2 = (const float*)d_in[4];
    const float* b2 = (const float*)d_in[5];
    float* out = (float*)d_out;

    const int Nn = N_NODES, E = N_EDGES;
    const int* srcp = ei;
    const int* dstp = ei + E;

    // d_out doubles as scratch: f16 GEMM A buffer (25.6 MB of the 51.2 MB).
    u16* Af = (u16*)d_out;

    char* p = (char*)d_ws;
    auto take = [&](size_t bytes) -> void* {
        void* r = (void*)p;
        p += (bytes + 255) & ~(size_t)255;
        return r;
    };
    u16* hs      = (u16*)take((size_t)8 * (Nn + 1) * 32 * 2);  // tile-major bf16
    u16* col16   = (u16*)take((size_t)E * 2);
    int* deg     = (int*)take((size_t)Nn * 4);
    int* cursor  = (int*)take((size_t)Nn * 4);
    int* rptr    = (int*)take((size_t)(Nn + 1) * 4);
    int* partial = (int*)take((size_t)NCHUNK * 1024 * 4);
    int* totals  = (int*)take(64 * 4);
    u16* W1t     = (u16*)take(256 * 256 * 2);
    u16* W2t     = (u16*)take(256 * 256 * 2);

    prep_fused<<<SPLIT_BLKS + ZERO_BLKS + 512, 256, 0, stream>>>(
        x, Af, W1, W2, W1t, W2t, deg, (u32*)hs);
    deg_kernel<<<E / 256, 256, 0, stream>>>(dstp, deg, E);
    scan1_kernel<<<NCHUNK, 1024, 0, stream>>>(deg, partial, totals, Nn);
    scan3_kernel<<<ZERO_BLKS, 256, 0, stream>>>(deg, partial, totals, rptr, cursor, Nn);
    fill_kernel<<<E / 256, 256, 0, stream>>>(srcp, dstp, cursor, col16, E);

    const int gm = (Nn + 127) / 128;           // 391
    const int aggblocks = ((Nn + 31) / 32) * 8;  // 1563 * 8 = 12504
    // layer 1
    gemm_f16_kernel<<<dim3(gm, 2), 256, 0, stream>>>(Af, W1t, deg, hs, Nn);
    agg_kernel<<<aggblocks, 256, 0, stream>>>(hs, rptr, col16, b1, Af, nullptr, 0, Nn);
    // layer 2
    gemm_f16_kernel<<<dim3(gm, 2), 256, 0, stream>>>(Af, W2t, deg, hs, Nn);
    agg_kernel<<<aggblocks, 256, 0, stream>>>(hs, rptr, col16, b2, nullptr, out, 1, Nn);
}